// Round 1
// baseline (224.504 us; speedup 1.0000x reference)
//
#include <hip/hip_runtime.h>

// Problem constants (from reference)
#define BQ 2
#define HQ 16
#define SQ 8192
#define DQ 128
#define LW 32        // window length
#define STR 16       // stride
#define NWIN 511     // (8192-32)/16 + 1
#define NBLK 512     // NWIN + 1 zero block
#define WPB 8        // windows per workgroup
#define NWG_PER_HEAD 64   // ceil(511/8)

typedef float f32x4 __attribute__((ext_vector_type(4)));
typedef short s16x8 __attribute__((ext_vector_type(8)));

// XOR swizzle: spreads stride-512B row reads across banks (guide G4 / T2).
static __device__ __forceinline__ unsigned swz(unsigned b) {
    return b ^ (((b >> 9) & 7u) << 4);
}

static __device__ __forceinline__ short f2bf(float f) {
    __bf16 h = (__bf16)f;
    return __builtin_bit_cast(short, h);
}

// ---- pass 0: convert weights f32 -> bf16 into workspace ----
// layout in ws: wd_bf[5][128][256] (163840 shorts) then wstop_bf[128][128] (16384 shorts)
__global__ void convw_kernel(const float* __restrict__ wd,
                             const float* __restrict__ wstop,
                             short* __restrict__ o) {
    int i = blockIdx.x * 256 + threadIdx.x;
    if (i < 163840) {
        o[i] = f2bf(wd[i]);
    } else if (i < 180224) {
        o[i] = f2bf(wstop[i - 163840]);
    }
}

// ---- pass 1: zero the prepended zero-block outputs (silu chain of 0 -> 0) ----
__global__ void zero_kernel(float* __restrict__ out) {
    int i = blockIdx.x * 256 + threadIdx.x;  // 4096 = 32 heads * 128
    int bh = i >> 7, d = i & 127;
    out[(size_t)bh * NBLK * DQ + d] = 0.f;
}

// ---- pass 2: fused compressor ----
// grid: 32 heads * 64 window-groups = 2048 blocks, 512 threads (8 waves)
__global__ __launch_bounds__(512, 2)
void fused_kernel(const float* __restrict__ kin,
                  const float* __restrict__ pe,
                  const short* __restrict__ wdb,   // bf16 weights in ws
                  float* __restrict__ out) {
    __shared__ __align__(16) unsigned char lds[98304];  // buf0 64KB @0, buf1 32KB @65536
    const short* wsb = wdb + 163840;

    const int bh = blockIdx.x >> 6;          // 0..31
    const int w0 = (blockIdx.x & 63) * WPB;  // first window of this group
    const int tid = threadIdx.x;

    // ---------- Phase A: build x = k[window]+pe as bf16 into buf0 (swizzled) ----------
    const float* kb = kin + (size_t)bh * SQ * DQ;
    #pragma unroll
    for (int it = 0; it < 8; ++it) {
        int task = tid + it * 512;        // 4096 tasks = 8 win * 32 rows * 16 chunks
        int wi  = task >> 9;
        int rem = task & 511;
        int r   = rem >> 4;               // row in window 0..31
        int c8  = rem & 15;               // 8-float chunk 0..15
        int w = w0 + wi;
        int srow = STR * w + r;
        if (srow > SQ - 1) srow = SQ - 1; // clamp for the padded (invalid) window
        const float* kp = kb + (size_t)srow * DQ + c8 * 8;
        const float* pp = pe + r * DQ + c8 * 8;
        f32x4 a0 = *(const f32x4*)kp;
        f32x4 a1 = *(const f32x4*)(kp + 4);
        f32x4 p0 = *(const f32x4*)pp;
        f32x4 p1 = *(const f32x4*)(pp + 4);
        s16x8 v;
        v[0] = f2bf(a0[0] + p0[0]); v[1] = f2bf(a0[1] + p0[1]);
        v[2] = f2bf(a0[2] + p0[2]); v[3] = f2bf(a0[3] + p0[3]);
        v[4] = f2bf(a1[0] + p1[0]); v[5] = f2bf(a1[1] + p1[1]);
        v[6] = f2bf(a1[2] + p1[2]); v[7] = f2bf(a1[3] + p1[3]);
        unsigned bb = (unsigned)(((wi * 32 + r) << 8) + (c8 << 4));
        *(s16x8*)(lds + swz(bb)) = v;
    }
    __syncthreads();

    const int lane = tid & 63;
    const int wave = tid >> 6;
    const int mgrp = wave >> 2;       // 0..1  (M half)
    const int ngrp = wave & 3;        // 0..3  (N quarter: 2 n-tiles)
    const int kl = lane >> 4;         // 0..3
    const int nl = lane & 15;         // 0..15

    // ---------- Phase B: 5 merge stages ----------
    for (int s = 0; s < 5; ++s) {
        const unsigned inoff  = (s & 1) ? 65536u : 0u;
        const unsigned outoff = (s & 1) ? 0u : 65536u;
        const short* W = wdb + s * 32768;

        // preload B fragments for this wave's two n-tiles (held in regs)
        s16x8 bfr[2][8];
        #pragma unroll
        for (int j = 0; j < 2; ++j) {
            int nt = ngrp * 2 + j;
            #pragma unroll
            for (int kt = 0; kt < 8; ++kt)
                bfr[j][kt] = *(const s16x8*)(W + (nt * 16 + nl) * 256 + kt * 32 + kl * 8);
        }

        const int Mout = (WPB * 16) >> s;          // 128,64,32,16,8
        const int mt_total = (Mout + 15) >> 4;     // 8,4,2,1,1
        const int mpg = mt_total >> 1;             // 4,2,1,0,0
        int mbeg, mend;
        if (mpg) { mbeg = mgrp * mpg; mend = mbeg + mpg; }
        else     { mbeg = 0; mend = (mgrp == 0) ? 1 : 0; }

        for (int m = mbeg; m < mend; ++m) {
            s16x8 afr[8];
            #pragma unroll
            for (int kt = 0; kt < 8; ++kt) {
                unsigned bb = (unsigned)(((m * 16 + nl) << 9) + (kt << 6) + (kl << 4));
                afr[kt] = *(const s16x8*)(lds + inoff + swz(bb));
            }
            f32x4 acc0 = {0.f, 0.f, 0.f, 0.f};
            f32x4 acc1 = {0.f, 0.f, 0.f, 0.f};
            #pragma unroll
            for (int kt = 0; kt < 8; ++kt) {
                acc0 = __builtin_amdgcn_mfma_f32_16x16x32_bf16(afr[kt], bfr[0][kt], acc0, 0, 0, 0);
                acc1 = __builtin_amdgcn_mfma_f32_16x16x32_bf16(afr[kt], bfr[1][kt], acc1, 0, 0, 0);
            }
            // epilogue: silu, cvt, write to out buffer (swizzled u16 stores)
            #pragma unroll
            for (int j = 0; j < 2; ++j) {
                f32x4 acc = j ? acc1 : acc0;
                int nt = ngrp * 2 + j;
                #pragma unroll
                for (int r4 = 0; r4 < 4; ++r4) {
                    int orow = m * 16 + kl * 4 + r4;
                    if (orow < Mout) {
                        float v = acc[r4];
                        v = v / (1.f + __expf(-v));
                        unsigned ob = (unsigned)((orow << 8) + ((nt * 16 + nl) << 1));
                        *(short*)(lds + outoff + swz(ob)) = f2bf(v);
                    }
                }
            }
        }
        __syncthreads();
    }

    // ---------- Phase C: w_stop (no activation), write f32 to global ----------
    // input: buf1 (stage 4 output), 8 rows of 128, row stride 256B
    {
        s16x8 bfr[2][4];
        #pragma unroll
        for (int j = 0; j < 2; ++j) {
            int nt = ngrp * 2 + j;
            #pragma unroll
            for (int kt = 0; kt < 4; ++kt)
                bfr[j][kt] = *(const s16x8*)(wsb + (nt * 16 + nl) * 128 + kt * 32 + kl * 8);
        }
        if (mgrp == 0) {
            s16x8 afr[4];
            #pragma unroll
            for (int kt = 0; kt < 4; ++kt) {
                unsigned bb = (unsigned)((nl << 8) + (kt << 6) + (kl << 4));
                afr[kt] = *(const s16x8*)(lds + 65536u + swz(bb));
            }
            f32x4 acc0 = {0.f, 0.f, 0.f, 0.f};
            f32x4 acc1 = {0.f, 0.f, 0.f, 0.f};
            #pragma unroll
            for (int kt = 0; kt < 4; ++kt) {
                acc0 = __builtin_amdgcn_mfma_f32_16x16x32_bf16(afr[kt], bfr[0][kt], acc0, 0, 0, 0);
                acc1 = __builtin_amdgcn_mfma_f32_16x16x32_bf16(afr[kt], bfr[1][kt], acc1, 0, 0, 0);
            }
            #pragma unroll
            for (int j = 0; j < 2; ++j) {
                f32x4 acc = j ? acc1 : acc0;
                int nt = ngrp * 2 + j;
                #pragma unroll
                for (int r4 = 0; r4 < 4; ++r4) {
                    int wi = kl * 4 + r4;          // window index within group
                    int w = w0 + wi;
                    if (wi < WPB && w < NWIN) {
                        out[((size_t)bh * NBLK + (w + 1)) * DQ + nt * 16 + nl] = acc[r4];
                    }
                }
            }
        }
    }
}

extern "C" void kernel_launch(void* const* d_in, const int* in_sizes, int n_in,
                              void* d_out, int out_size, void* d_ws, size_t ws_size,
                              hipStream_t stream) {
    const float* kin   = (const float*)d_in[0];
    const float* pe    = (const float*)d_in[1];
    const float* wdown = (const float*)d_in[2];
    const float* wstop = (const float*)d_in[3];
    float* out = (float*)d_out;
    short* wbf = (short*)d_ws;   // 180224 shorts = 352.4 KB

    convw_kernel<<<704, 256, 0, stream>>>(wdown, wstop, wbf);
    zero_kernel<<<16, 256, 0, stream>>>(out);
    fused_kernel<<<BQ * HQ * NWG_PER_HEAD, 512, 0, stream>>>(kin, pe, wbf, out);
}

// Round 2
// 155.914 us; speedup vs baseline: 1.4399x; 1.4399x over previous
//
#include <hip/hip_runtime.h>

// Problem constants (from reference)
#define BQ 2
#define HQ 16
#define SQ 8192
#define DQ 128
#define LW 32        // window length
#define STR 16       // stride
#define NWIN 511     // (8192-32)/16 + 1
#define NBLK 512     // NWIN + 1 zero block
#define WPB 8        // windows per workgroup
#define NWG_PER_HEAD 64   // ceil(511/8)

typedef float f32x4 __attribute__((ext_vector_type(4)));
typedef short s16x8 __attribute__((ext_vector_type(8)));

// XOR swizzle: spreads stride-512B row reads across banks (guide G4 / T2).
// Applied to GLOBAL lds byte offsets; all region bases are multiples of 4096
// so writer/reader swizzles agree.
static __device__ __forceinline__ unsigned swz(unsigned b) {
    return b ^ (((b >> 9) & 7u) << 4);
}

static __device__ __forceinline__ short f2bf(float f) {
    __bf16 h = (__bf16)f;
    return __builtin_bit_cast(short, h);
}

static __device__ __forceinline__ float silu(float v) {
    return v / (1.f + __expf(-v));
}

// ---- pass 0: convert weights f32 -> bf16 into workspace ----
// ws layout: wd_bf[5][128][256] (163840 shorts) then wstop_bf[128][128] (16384)
__global__ void convw_kernel(const float* __restrict__ wd,
                             const float* __restrict__ wstop,
                             short* __restrict__ o) {
    int i = blockIdx.x * 256 + threadIdx.x;
    if (i < 163840) {
        o[i] = f2bf(wd[i]);
    } else if (i < 180224) {
        o[i] = f2bf(wstop[i - 163840]);
    }
}

// ---- pass 1: zero the prepended zero-block outputs (silu chain of 0 -> 0) ----
__global__ void zero_kernel(float* __restrict__ out) {
    int i = blockIdx.x * 256 + threadIdx.x;  // 4096 = 32 heads * 128
    int bh = i >> 7, d = i & 127;
    out[(size_t)bh * NBLK * DQ + d] = 0.f;
}

// ---- pass 2: fused compressor ----
// grid: 32 heads * 64 window-groups = 2048 blocks, 512 threads (8 waves).
// LDS 48KB -> 3 WG/CU (24 waves/CU); wave w owns n-tile w for all stages.
// Phase A + stage 0 stream in 4 chunks of 2 windows through a 16KB buffer.
__global__ __launch_bounds__(512, 6)
void fused_kernel(const float* __restrict__ kin,
                  const float* __restrict__ pe,
                  const short* __restrict__ wdb,   // bf16 weights in ws
                  float* __restrict__ out) {
    // bufIn @0 (16KB: 2 windows x 32 rows x 256B), pp @16384 (32KB max)
    __shared__ __align__(16) unsigned char lds[49152];
    const short* wsb = wdb + 163840;

    const int bh = blockIdx.x >> 6;          // 0..31
    const int w0 = (blockIdx.x & 63) * WPB;  // first window of this group
    const int tid  = threadIdx.x;
    const int lane = tid & 63;
    const int nt   = tid >> 6;               // wave index == n-tile 0..7
    const int kl   = lane >> 4;              // 0..3
    const int nl   = lane & 15;              // 0..15

    const float* kb = kin + (size_t)bh * SQ * DQ;

    // stage-0 B fragments (held across the chunk loop): n-tile nt, K=256
    s16x8 b0[8];
    #pragma unroll
    for (int kt = 0; kt < 8; ++kt)
        b0[kt] = *(const s16x8*)(wdb + (nt * 16 + nl) * 256 + kt * 32 + kl * 8);

    // ---------- chunks: load 2 windows -> bufIn, stage0 -> pp rows 32c..32c+31
    for (int c = 0; c < 4; ++c) {
        #pragma unroll
        for (int it = 0; it < 2; ++it) {
            int task = tid + it * 512;        // 1024 = 2 win * 32 rows * 16 chunks
            int wi  = task >> 9;              // 0..1
            int rem = task & 511;
            int r   = rem >> 4;               // 0..31
            int c8  = rem & 15;               // 0..15
            int w = w0 + c * 2 + wi;
            int srow = STR * w + r;
            if (srow > SQ - 1) srow = SQ - 1; // clamp padded window (discarded later)
            const float* kp = kb + (size_t)srow * DQ + c8 * 8;
            const float* pp = pe + r * DQ + c8 * 8;
            f32x4 a0 = *(const f32x4*)kp;
            f32x4 a1 = *(const f32x4*)(kp + 4);
            f32x4 p0 = *(const f32x4*)pp;
            f32x4 p1 = *(const f32x4*)(pp + 4);
            s16x8 v;
            v[0] = f2bf(a0[0] + p0[0]); v[1] = f2bf(a0[1] + p0[1]);
            v[2] = f2bf(a0[2] + p0[2]); v[3] = f2bf(a0[3] + p0[3]);
            v[4] = f2bf(a1[0] + p1[0]); v[5] = f2bf(a1[1] + p1[1]);
            v[6] = f2bf(a1[2] + p1[2]); v[7] = f2bf(a1[3] + p1[3]);
            unsigned bb = (unsigned)(((wi * 32 + r) << 8) + (c8 << 4));
            *(s16x8*)(lds + swz(bb)) = v;
        }
        __syncthreads();

        // stage 0 on this chunk: 2 m-tiles (32 output rows)
        #pragma unroll
        for (int mm = 0; mm < 2; ++mm) {
            s16x8 afr[8];
            #pragma unroll
            for (int kt = 0; kt < 8; ++kt) {
                unsigned bb = (unsigned)(((mm * 16 + nl) << 9) + (kt << 6) + (kl << 4));
                afr[kt] = *(const s16x8*)(lds + swz(bb));
            }
            f32x4 ae = {0.f, 0.f, 0.f, 0.f};
            f32x4 ao = {0.f, 0.f, 0.f, 0.f};
            #pragma unroll
            for (int kt = 0; kt < 8; kt += 2) {
                ae = __builtin_amdgcn_mfma_f32_16x16x32_bf16(afr[kt],     b0[kt],     ae, 0, 0, 0);
                ao = __builtin_amdgcn_mfma_f32_16x16x32_bf16(afr[kt + 1], b0[kt + 1], ao, 0, 0, 0);
            }
            #pragma unroll
            for (int r4 = 0; r4 < 4; ++r4) {
                float v = silu(ae[r4] + ao[r4]);
                int orow = c * 32 + mm * 16 + kl * 4 + r4;   // < 128 always
                unsigned ob = (unsigned)(16384 + (orow << 8) + ((nt * 16 + nl) << 1));
                *(short*)(lds + swz(ob)) = f2bf(v);
            }
        }
        __syncthreads();
    }

    // ---------- stages 1..4: ping-pong @16384 <-> @0 ----------
    for (int s = 1; s <= 4; ++s) {
        const short* W = wdb + s * 32768;
        s16x8 bfr[8];
        #pragma unroll
        for (int kt = 0; kt < 8; ++kt)
            bfr[kt] = *(const s16x8*)(W + (nt * 16 + nl) * 256 + kt * 32 + kl * 8);

        const unsigned inoff  = (s & 1) ? 16384u : 0u;
        const unsigned outoff = 16384u - inoff;
        const int Mout = 128 >> s;           // 64,32,16,8
        const int mt = (Mout + 15) >> 4;     // 4,2,1,1

        for (int m = 0; m < mt; ++m) {
            s16x8 afr[8];
            #pragma unroll
            for (int kt = 0; kt < 8; ++kt) {
                unsigned bb = inoff + (unsigned)(((m * 16 + nl) << 9) + (kt << 6) + (kl << 4));
                afr[kt] = *(const s16x8*)(lds + swz(bb));
            }
            f32x4 ae = {0.f, 0.f, 0.f, 0.f};
            f32x4 ao = {0.f, 0.f, 0.f, 0.f};
            #pragma unroll
            for (int kt = 0; kt < 8; kt += 2) {
                ae = __builtin_amdgcn_mfma_f32_16x16x32_bf16(afr[kt],     bfr[kt],     ae, 0, 0, 0);
                ao = __builtin_amdgcn_mfma_f32_16x16x32_bf16(afr[kt + 1], bfr[kt + 1], ao, 0, 0, 0);
            }
            #pragma unroll
            for (int r4 = 0; r4 < 4; ++r4) {
                int orow = m * 16 + kl * 4 + r4;
                if (orow < Mout) {
                    float v = silu(ae[r4] + ao[r4]);
                    unsigned ob = outoff + (unsigned)((orow << 8) + ((nt * 16 + nl) << 1));
                    *(short*)(lds + swz(ob)) = f2bf(v);
                }
            }
        }
        __syncthreads();
    }

    // ---------- w_stop (no activation), input @16384 (8 valid rows), K=128 ----
    {
        s16x8 bfr[4];
        #pragma unroll
        for (int kt = 0; kt < 4; ++kt)
            bfr[kt] = *(const s16x8*)(wsb + (nt * 16 + nl) * 128 + kt * 32 + kl * 8);
        s16x8 afr[4];
        #pragma unroll
        for (int kt = 0; kt < 4; ++kt) {
            unsigned bb = 16384u + (unsigned)((nl << 8) + (kt << 6) + (kl << 4));
            afr[kt] = *(const s16x8*)(lds + swz(bb));
        }
        f32x4 ae = {0.f, 0.f, 0.f, 0.f};
        f32x4 ao = {0.f, 0.f, 0.f, 0.f};
        ae = __builtin_amdgcn_mfma_f32_16x16x32_bf16(afr[0], bfr[0], ae, 0, 0, 0);
        ao = __builtin_amdgcn_mfma_f32_16x16x32_bf16(afr[1], bfr[1], ao, 0, 0, 0);
        ae = __builtin_amdgcn_mfma_f32_16x16x32_bf16(afr[2], bfr[2], ae, 0, 0, 0);
        ao = __builtin_amdgcn_mfma_f32_16x16x32_bf16(afr[3], bfr[3], ao, 0, 0, 0);
        #pragma unroll
        for (int r4 = 0; r4 < 4; ++r4) {
            int wi = kl * 4 + r4;          // window index within group (0..15)
            int w = w0 + wi;
            if (wi < WPB && w < NWIN) {
                out[((size_t)bh * NBLK + (w + 1)) * DQ + nt * 16 + nl] = ae[r4] + ao[r4];
            }
        }
    }
}

extern "C" void kernel_launch(void* const* d_in, const int* in_sizes, int n_in,
                              void* d_out, int out_size, void* d_ws, size_t ws_size,
                              hipStream_t stream) {
    const float* kin   = (const float*)d_in[0];
    const float* pe    = (const float*)d_in[1];
    const float* wdown = (const float*)d_in[2];
    const float* wstop = (const float*)d_in[3];
    float* out = (float*)d_out;
    short* wbf = (short*)d_ws;   // 180224 shorts = 352.4 KB

    convw_kernel<<<704, 256, 0, stream>>>(wdown, wstop, wbf);
    zero_kernel<<<16, 256, 0, stream>>>(out);
    fused_kernel<<<BQ * HQ * NWG_PER_HEAD, 512, 0, stream>>>(kin, pe, wbf, out);
}